// Round 1
// baseline (2263.593 us; speedup 1.0000x reference)
//
#include <hip/hip_runtime.h>
#include <hip/hip_bf16.h>

// ---------------------------------------------------------------------------
// ScaledDotProductAttentionMemory: fused MHA with M=40 memory slots.
//   out  (8,1024,1024) fp32   = chunk 0 of d_out
//   att  (8,16,1024,1064) fp32 = chunk 1 of d_out
// Workspace usage: ~78 MB (bf16 staging buffers).
// ---------------------------------------------------------------------------

#define B_ 8
#define NQ 1024
#define NK 1024
#define DM 1024
#define H_ 16
#define DK 64
#define NKM 1064   // nk + M
#define NKP 1088   // padded to multiple of 32

typedef __attribute__((ext_vector_type(8))) short bf16x8;
typedef __attribute__((ext_vector_type(4))) float f32x4;

static __device__ __forceinline__ short f2bf(float x) {
    __hip_bfloat16 h = __float2bfloat16(x);
    return __builtin_bit_cast(short, h);
}

static __device__ __forceinline__ bf16x8 pack8(const float* __restrict__ p) {
    float4 f0 = *(const float4*)p;
    float4 f1 = *(const float4*)(p + 4);
    bf16x8 a;
    a[0] = f2bf(f0.x); a[1] = f2bf(f0.y); a[2] = f2bf(f0.z); a[3] = f2bf(f0.w);
    a[4] = f2bf(f1.x); a[5] = f2bf(f1.y); a[6] = f2bf(f1.z); a[7] = f2bf(f1.w);
    return a;
}

// --- mask dtype probe: bool(1B) vs int32(4B) ------------------------------
__global__ void detect_mask_kernel(const unsigned int* __restrict__ m, int n_dwords,
                                   int* __restrict__ flag) {
    __shared__ int any_big;
    if (threadIdx.x == 0) any_big = 0;
    __syncthreads();
    for (int i = threadIdx.x; i < n_dwords; i += blockDim.x)
        if (m[i] > 1u) any_big = 1;
    __syncthreads();
    if (threadIdx.x == 0) *flag = any_big ? 0 : 1;   // 1 => int32, 0 => bytes
}

// --- W (K x N) fp32 -> WT (N x K) bf16 -------------------------------------
__global__ void transpose_w_kernel(const float* __restrict__ W, short* __restrict__ WT) {
    __shared__ float t[32][33];
    int tx = threadIdx.x & 31, ty = threadIdx.x >> 5;   // 256 threads: ty 0..7
    int k0 = blockIdx.x * 32, n0 = blockIdx.y * 32;
#pragma unroll
    for (int r = 0; r < 4; r++)
        t[ty + 8 * r][tx] = W[(size_t)(k0 + ty + 8 * r) * DM + n0 + tx];
    __syncthreads();
#pragma unroll
    for (int r = 0; r < 4; r++)
        WT[(size_t)(n0 + ty + 8 * r) * DM + k0 + tx] = f2bf(t[tx][ty + 8 * r]);
}

// --- memory-slot rows of Kh / Vt (rows 1024..1087; zeros past 1063) --------
__global__ void fill_mem_kernel(const float* __restrict__ m_k, const float* __restrict__ m_v,
                                short* __restrict__ Kh, short* __restrict__ Vt) {
    int idx = blockIdx.x * 256 + threadIdx.x;   // B_*H_*64*64 total
    int d  = idx & 63;
    int r  = (idx >> 6) & 63;                   // row - 1024
    int bh = idx >> 12;                         // b*16 + h
    int h  = bh & 15;
    float kv = 0.f, vv = 0.f;
    if (r < 40) {
        kv = 8.0f * m_k[(size_t)(r * H_ + h) * DK + d];          // sqrt(DK)=8
        vv = 6.324555320336759f * m_v[(size_t)(r * H_ + h) * DK + d]; // sqrt(M)
    }
    int kk = 1024 + r;
    Kh[(((size_t)bh * NKP + kk) << 6) + d] = f2bf(kv);
    Vt[((size_t)bh * DK + d) * NKP + kk]   = f2bf(vv);
}

// --- generic 16x16-per-wave MFMA GEMM: C = A @ WT^T + bias -----------------
// MODE 0: Q proj -> Qh[b][h][q][d]      (A fp32)
// MODE 1: K proj -> Kh[b][h][kk][d]     (A fp32)
// MODE 2: V proj -> Vt[b][h][d][kk]     (A fp32)
// MODE 3: out proj -> outF[row][col] fp32 (A bf16)
template <int MODE>
__global__ void gemm16_kernel(const float* __restrict__ Af, const short* __restrict__ Ab,
                              const short* __restrict__ BT, const float* __restrict__ bias,
                              float* __restrict__ outF, short* __restrict__ outB,
                              int Ntiles) {
    int lane = threadIdx.x & 63;
    int w = blockIdx.x * (blockDim.x >> 6) + (threadIdx.x >> 6);
    int ti = w / Ntiles, tj = w % Ntiles;
    int ar = ti * 16 + (lane & 15);
    int br = tj * 16 + (lane & 15);
    int koff = (lane >> 4) * 8;
    f32x4 acc = {0.f, 0.f, 0.f, 0.f};
    for (int k0 = 0; k0 < DM; k0 += 32) {
        int ak = k0 + koff;
        bf16x8 a;
        if (MODE == 3) {
            a = *(const bf16x8*)(Ab + (size_t)ar * DM + ak);
        } else {
            a = pack8(Af + (size_t)ar * DM + ak);
        }
        bf16x8 bb = *(const bf16x8*)(BT + (size_t)br * DM + ak);
        acc = __builtin_amdgcn_mfma_f32_16x16x32_bf16(a, bb, acc, 0, 0, 0);
    }
    int col = tj * 16 + (lane & 15);
    float bval = bias[col];
    int row0 = ti * 16 + (lane >> 4) * 4;
#pragma unroll
    for (int r = 0; r < 4; r++) {
        int row = row0 + r;
        float v = acc[r] + bval;
        if (MODE == 0) {
            int b = row >> 10, q = row & 1023, h = col >> 6, d = col & 63;
            outB[(((size_t)(b * H_ + h) * NQ + q) << 6) + d] = f2bf(v);
        } else if (MODE == 1) {
            int b = row >> 10, kk = row & 1023, h = col >> 6, d = col & 63;
            outB[(((size_t)(b * H_ + h) * NKP + kk) << 6) + d] = f2bf(v);
        } else if (MODE == 2) {
            int b = row >> 10, kk = row & 1023, h = col >> 6, d = col & 63;
            outB[((size_t)(b * H_ + h) * DK + d) * NKP + kk] = f2bf(v);
        } else {
            outF[(size_t)row * DM + col] = v;
        }
    }
}

// --- logits: S = Qh @ Kh^T / 8, mask applied, fp32 into att output ---------
__global__ void logits_kernel(const short* __restrict__ Qh, const short* __restrict__ Kh,
                              const unsigned char* __restrict__ mb, const int* __restrict__ mi,
                              const int* __restrict__ flag, float* __restrict__ att) {
    int lane = threadIdx.x & 63;
    int w = blockIdx.x * (blockDim.x >> 6) + (threadIdx.x >> 6);
    int bh = w / (64 * 67);
    int rem = w % (64 * 67);
    int qt = rem / 67, kt = rem % 67;
    const short* Qb = Qh + (size_t)bh * NQ * DK;
    const short* Kb = Kh + (size_t)bh * NKP * DK;
    int koff = (lane >> 4) * 8;
    f32x4 acc = {0.f, 0.f, 0.f, 0.f};
#pragma unroll
    for (int k0 = 0; k0 < DK; k0 += 32) {
        bf16x8 a = *(const bf16x8*)(Qb + (size_t)(qt * 16 + (lane & 15)) * DK + k0 + koff);
        bf16x8 b = *(const bf16x8*)(Kb + (size_t)(kt * 16 + (lane & 15)) * DK + k0 + koff);
        acc = __builtin_amdgcn_mfma_f32_16x16x32_bf16(a, b, acc, 0, 0, 0);
    }
    int kk = kt * 16 + (lane & 15);
    if (kk >= NKM) return;
    bool is32 = (*flag) != 0;
    int q0 = qt * 16 + (lane >> 4) * 4;
#pragma unroll
    for (int r = 0; r < 4; r++) {
        int q = q0 + r;
        float v = acc[r] * 0.125f;
        if (kk < NK) {
            size_t midx = ((size_t)bh * NQ + q) * NK + kk;
            int mval = is32 ? mi[midx] : (int)mb[midx];
            if (mval) v = -INFINITY;
        }
        att[((size_t)bh * NQ + q) * NKM + kk] = v;
    }
}

// --- row softmax in place over 1064 columns, 1 wave per row ----------------
__global__ void softmax_kernel(float* __restrict__ att) {
    int row = blockIdx.x * (blockDim.x >> 6) + (threadIdx.x >> 6);
    int lane = threadIdx.x & 63;
    float* p = att + (size_t)row * NKM;
    float v[17];
    float mx = -INFINITY;
#pragma unroll
    for (int i = 0; i < 17; i++) {
        int c = lane + i * 64;
        v[i] = (c < NKM) ? p[c] : -INFINITY;
        mx = fmaxf(mx, v[i]);
    }
#pragma unroll
    for (int o = 32; o; o >>= 1) mx = fmaxf(mx, __shfl_xor(mx, o));
    float s = 0.f;
#pragma unroll
    for (int i = 0; i < 17; i++) {
        int c = lane + i * 64;
        v[i] = (c < NKM) ? __expf(v[i] - mx) : 0.f;
        s += v[i];
    }
#pragma unroll
    for (int o = 32; o; o >>= 1) s += __shfl_xor(s, o);
    float inv = 1.f / s;
#pragma unroll
    for (int i = 0; i < 17; i++) {
        int c = lane + i * 64;
        if (c < NKM) p[c] = v[i] * inv;
    }
}

// --- PV: O = att @ V -> Ow[b*1024+q][h*64+d] bf16 ---------------------------
__global__ void pv_kernel(const float* __restrict__ att, const short* __restrict__ Vt,
                          short* __restrict__ Ow) {
    int lane = threadIdx.x & 63;
    int w = blockIdx.x * (blockDim.x >> 6) + (threadIdx.x >> 6);
    int bh = w >> 8;            // 64 qtiles * 4 dtiles per bh
    int rem = w & 255;
    int qt = rem >> 2, dt = rem & 3;
    const float* Ab = att + (size_t)bh * NQ * NKM;
    const short* Vb = Vt + (size_t)bh * DK * NKP;
    int koff = (lane >> 4) * 8;
    f32x4 acc = {0.f, 0.f, 0.f, 0.f};
    for (int k0 = 0; k0 < NKP; k0 += 32) {
        int ck = k0 + koff;
        bf16x8 a = {0, 0, 0, 0, 0, 0, 0, 0};
        if (ck < NKM) {   // ck multiple of 8, NKM multiple of 8 -> full 8 valid
            a = pack8(Ab + (size_t)(qt * 16 + (lane & 15)) * NKM + ck);
        }
        bf16x8 b = *(const bf16x8*)(Vb + (size_t)(dt * 16 + (lane & 15)) * NKP + ck);
        acc = __builtin_amdgcn_mfma_f32_16x16x32_bf16(a, b, acc, 0, 0, 0);
    }
    int h = bh & 15, b = bh >> 4;
    int d = dt * 16 + (lane & 15);
    int q0 = qt * 16 + (lane >> 4) * 4;
#pragma unroll
    for (int r = 0; r < 4; r++)
        Ow[(size_t)(b * NQ + q0 + r) * DM + h * DK + d] = f2bf(acc[r]);
}

extern "C" void kernel_launch(void* const* d_in, const int* in_sizes, int n_in,
                              void* d_out, int out_size, void* d_ws, size_t ws_size,
                              hipStream_t stream) {
    const float* queries = (const float*)d_in[0];
    const float* keys    = (const float*)d_in[1];
    const float* values  = (const float*)d_in[2];
    const void*  mask    = d_in[3];
    const float* Wq = (const float*)d_in[4];
    const float* bq = (const float*)d_in[5];
    const float* Wk = (const float*)d_in[6];
    const float* bk = (const float*)d_in[7];
    const float* Wv = (const float*)d_in[8];
    const float* bv = (const float*)d_in[9];
    const float* Wo = (const float*)d_in[10];
    const float* bo = (const float*)d_in[11];
    const float* m_k = (const float*)d_in[12];
    const float* m_v = (const float*)d_in[13];

    // workspace layout (shorts)
    short* WqT = (short*)d_ws;
    short* WkT = WqT + (size_t)DM * DM;
    short* WvT = WkT + (size_t)DM * DM;
    short* WoT = WvT + (size_t)DM * DM;
    short* Qh  = WoT + (size_t)DM * DM;                 // [128][1024][64]
    short* Kh  = Qh + (size_t)B_ * H_ * NQ * DK;        // [128][1088][64]
    short* Vt  = Kh + (size_t)B_ * H_ * NKP * DK;       // [128][64][1088]
    short* Ow  = Vt + (size_t)B_ * H_ * DK * NKP;       // [8192][1024]
    int* flag  = (int*)(Ow + (size_t)B_ * NQ * DM);

    float* outO = (float*)d_out;                         // 8*1024*1024
    float* att  = outO + (size_t)B_ * NQ * DM;           // 8*16*1024*1064

    // 1) mask dtype probe
    detect_mask_kernel<<<1, 256, 0, stream>>>((const unsigned int*)mask, 4096, flag);

    // 2) weight transposes (fp32 -> bf16, K x N -> N x K)
    dim3 tg(32, 32);
    transpose_w_kernel<<<tg, 256, 0, stream>>>(Wq, WqT);
    transpose_w_kernel<<<tg, 256, 0, stream>>>(Wk, WkT);
    transpose_w_kernel<<<tg, 256, 0, stream>>>(Wv, WvT);
    transpose_w_kernel<<<tg, 256, 0, stream>>>(Wo, WoT);

    // 3) projections: 512 row-tiles x 64 col-tiles = 32768 waves -> 8192 blocks
    gemm16_kernel<0><<<8192, 256, 0, stream>>>(queries, nullptr, WqT, bq, nullptr, Qh, 64);
    gemm16_kernel<1><<<8192, 256, 0, stream>>>(keys,    nullptr, WkT, bk, nullptr, Kh, 64);
    gemm16_kernel<2><<<8192, 256, 0, stream>>>(values,  nullptr, WvT, bv, nullptr, Vt, 64);

    // 4) memory slot rows + zero padding
    fill_mem_kernel<<<2048, 256, 0, stream>>>(m_k, m_v, Kh, Vt);

    // 5) masked logits -> att region (fp32)
    logits_kernel<<<(B_ * H_ * 64 * 67) / 4, 256, 0, stream>>>(
        Qh, Kh, (const unsigned char*)mask, (const int*)mask, flag, att);

    // 6) softmax in place (131072 rows, 4 rows/block)
    softmax_kernel<<<(B_ * H_ * NQ) / 4, 256, 0, stream>>>(att);

    // 7) O = att @ V  (128 bh * 256 tiles = 32768 waves -> 8192 blocks)
    pv_kernel<<<8192, 256, 0, stream>>>(att, Vt, Ow);

    // 8) out = Ow @ Wo + bo (fp32 out)
    gemm16_kernel<3><<<8192, 256, 0, stream>>>(nullptr, Ow, WoT, bo, outO, nullptr, 64);
}

// Round 2
// 1028.982 us; speedup vs baseline: 2.1998x; 2.1998x over previous
//
#include <hip/hip_runtime.h>
#include <hip/hip_bf16.h>

// ---------------------------------------------------------------------------
// ScaledDotProductAttentionMemory, round 1:
//  - fused logits+mask+softmax+att-write+PV kernel (saves ~1.7 GB HBM traffic)
//  - 128x128-tile double-buffered LDS MFMA GEMM for the 4 projections
// Outputs: out (8,1024,1024) fp32 ; att (8,16,1024,1064) fp32
// ---------------------------------------------------------------------------

#define B_ 8
#define NQ 1024
#define NK 1024
#define DM 1024
#define H_ 16
#define DK 64
#define NKM 1064   // nk + M
#define NKP 1104   // padded row length for Kh/Vt (covers PV fragment overreach)

typedef __attribute__((ext_vector_type(8))) short bf16x8;
typedef __attribute__((ext_vector_type(4))) float f32x4;
typedef __attribute__((ext_vector_type(4))) short short4v;

static __device__ __forceinline__ short f2bf(float x) {
    __hip_bfloat16 h = __float2bfloat16(x);
    return __builtin_bit_cast(short, h);
}

static __device__ __forceinline__ bf16x8 pack8(const float* __restrict__ p) {
    float4 f0 = *(const float4*)p;
    float4 f1 = *(const float4*)(p + 4);
    bf16x8 a;
    a[0] = f2bf(f0.x); a[1] = f2bf(f0.y); a[2] = f2bf(f0.z); a[3] = f2bf(f0.w);
    a[4] = f2bf(f1.x); a[5] = f2bf(f1.y); a[6] = f2bf(f1.z); a[7] = f2bf(f1.w);
    return a;
}

// --- mask dtype probe: bool(1B) vs int32(4B) -------------------------------
__global__ void detect_mask_kernel(const unsigned int* __restrict__ m, int n_dwords,
                                   int* __restrict__ flag) {
    __shared__ int any_big;
    if (threadIdx.x == 0) any_big = 0;
    __syncthreads();
    for (int i = threadIdx.x; i < n_dwords; i += blockDim.x)
        if (m[i] > 1u) any_big = 1;
    __syncthreads();
    if (threadIdx.x == 0) *flag = any_big ? 0 : 1;   // 1 => int32, 0 => bytes
}

// --- W (K x N) fp32 -> WT (N x K) bf16 --------------------------------------
__global__ void transpose_w_kernel(const float* __restrict__ W, short* __restrict__ WT) {
    __shared__ float t[32][33];
    int tx = threadIdx.x & 31, ty = threadIdx.x >> 5;
    int k0 = blockIdx.x * 32, n0 = blockIdx.y * 32;
#pragma unroll
    for (int r = 0; r < 4; r++)
        t[ty + 8 * r][tx] = W[(size_t)(k0 + ty + 8 * r) * DM + n0 + tx];
    __syncthreads();
#pragma unroll
    for (int r = 0; r < 4; r++)
        WT[(size_t)(n0 + ty + 8 * r) * DM + k0 + tx] = f2bf(t[tx][ty + 8 * r]);
}

// --- memory-slot rows of Kh / Vt (rows 1024..1103; zeros past 1063) --------
__global__ void fill_mem_kernel(const float* __restrict__ m_k, const float* __restrict__ m_v,
                                short* __restrict__ Kh, short* __restrict__ Vt) {
    int blk = blockIdx.x;           // 128 bh * 20 row-groups
    int bh = blk / 20, rb = blk % 20;
    int r = rb * 4 + (threadIdx.x >> 6);    // 0..79
    int d = threadIdx.x & 63;
    int h = bh & 15;
    float kv = 0.f, vv = 0.f;
    if (r < 40) {
        kv = 8.0f * m_k[(size_t)(r * H_ + h) * DK + d];               // sqrt(DK)=8
        vv = 6.324555320336759f * m_v[(size_t)(r * H_ + h) * DK + d]; // sqrt(M)
    }
    int kk = 1024 + r;
    Kh[((size_t)bh * NKP + kk) * 64 + d] = f2bf(kv);
    Vt[((size_t)bh * 64 + d) * NKP + kk] = f2bf(vv);
}

// ---------------------------------------------------------------------------
// Tiled GEMM: C[MxN] = A[Mx1024] @ BT[Nx1024]^T + bias, M=8192, N=1024.
// 128x128 tile, BK=32, double-buffered LDS, 4 waves x (64x64 acc).
// LDS writes XOR-swizzled (byte slot ^= row&3) and ds_read_b128 uses the
// same involution (both-sides rule).
// MODE 0: Q proj -> Qh[bh][q][64]        (A fp32)
// MODE 1: K proj -> Kh[bh][kk(NKP)][64]  (A fp32)
// MODE 2: V proj -> Vt[bh][d][kk(NKP)]   (A fp32)
// MODE 3: out proj -> outF fp32 [8192][1024] (A bf16)
// ---------------------------------------------------------------------------
template <int MODE>
__global__ __launch_bounds__(256) void gemm_tile_kernel(
    const float* __restrict__ Af, const short* __restrict__ Ab,
    const short* __restrict__ BT, const float* __restrict__ bias,
    float* __restrict__ outF, short* __restrict__ outB) {
    __shared__ short As[2][4096];   // [128][32] bf16, swizzled
    __shared__ short Bs[2][4096];

    const int tid = threadIdx.x;
    const int lane = tid & 63;
    const int wid = tid >> 6;
    // XCD swizzle: 512 blocks, group 64 consecutive swz per XCD -> 8 mt panels
    int swz = (blockIdx.x & 7) * 64 + (blockIdx.x >> 3);
    const int mt = swz >> 3;        // 0..63
    const int nt = swz & 7;         // 0..7
    const int brow = mt * 128, bcol = nt * 128;
    const int wr = wid >> 1, wc = wid & 1;
    const int l15 = lane & 15, lg = lane >> 4;

    f32x4 acc[4][4];
#pragma unroll
    for (int m = 0; m < 4; m++)
#pragma unroll
        for (int n = 0; n < 4; n++) acc[m][n] = f32x4{0.f, 0.f, 0.f, 0.f};

    auto stage = [&](int buf, int k0) {
#pragma unroll
        for (int i = 0; i < 2; i++) {
            int c = tid + i * 256;          // 0..511 chunks of 16B
            int row = c >> 2, slot = c & 3;
            int sw = slot ^ (row & 3);
            bf16x8 av;
            if (MODE == 3) {
                av = *(const bf16x8*)(Ab + (size_t)(brow + row) * DM + k0 + slot * 8);
            } else {
                av = pack8(Af + (size_t)(brow + row) * DM + k0 + slot * 8);
            }
            *(bf16x8*)(&As[buf][row * 32 + sw * 8]) = av;
            bf16x8 bv = *(const bf16x8*)(BT + (size_t)(bcol + row) * DM + k0 + slot * 8);
            *(bf16x8*)(&Bs[buf][row * 32 + sw * 8]) = bv;
        }
    };

    stage(0, 0);
    for (int kt = 0; kt < 32; ++kt) {
        __syncthreads();                     // stage(kt) complete; compute(kt-1) done
        if (kt + 1 < 32) stage((kt + 1) & 1, (kt + 1) * 32);
        const short* Ab_ = As[kt & 1];
        const short* Bb_ = Bs[kt & 1];
        bf16x8 a[4], b[4];
#pragma unroll
        for (int m = 0; m < 4; m++) {
            int row = wr * 64 + m * 16 + l15;
            a[m] = *(const bf16x8*)(Ab_ + row * 32 + ((lg ^ (row & 3)) * 8));
        }
#pragma unroll
        for (int n = 0; n < 4; n++) {
            int row = wc * 64 + n * 16 + l15;
            b[n] = *(const bf16x8*)(Bb_ + row * 32 + ((lg ^ (row & 3)) * 8));
        }
#pragma unroll
        for (int m = 0; m < 4; m++)
#pragma unroll
            for (int n = 0; n < 4; n++)
                acc[m][n] = __builtin_amdgcn_mfma_f32_16x16x32_bf16(a[m], b[n], acc[m][n], 0, 0, 0);
    }

    // epilogue
#pragma unroll
    for (int n = 0; n < 4; n++) {
        int col = bcol + wc * 64 + n * 16 + l15;
        float bval = bias[col];
#pragma unroll
        for (int m = 0; m < 4; m++) {
            int row0 = brow + wr * 64 + m * 16 + lg * 4;
            if (MODE == 3) {
#pragma unroll
                for (int r = 0; r < 4; r++)
                    outF[(size_t)(row0 + r) * DM + col] = acc[m][n][r] + bval;
            } else if (MODE == 0) {
                int h = col >> 6, d = col & 63;
#pragma unroll
                for (int r = 0; r < 4; r++) {
                    int row = row0 + r;
                    int b = row >> 10, q = row & 1023;
                    outB[((size_t)(b * H_ + h) * NQ + q) * 64 + d] = f2bf(acc[m][n][r] + bval);
                }
            } else if (MODE == 1) {
                int h = col >> 6, d = col & 63;
#pragma unroll
                for (int r = 0; r < 4; r++) {
                    int row = row0 + r;
                    int b = row >> 10, kk = row & 1023;
                    outB[((size_t)(b * H_ + h) * NKP + kk) * 64 + d] = f2bf(acc[m][n][r] + bval);
                }
            } else {  // MODE 2: Vt[bh][d][kk], 4 consecutive kk -> short4
                int h = col >> 6, d = col & 63;
                int b = row0 >> 10, kk0 = row0 & 1023;
                short4v sv;
#pragma unroll
                for (int r = 0; r < 4; r++) sv[r] = f2bf(acc[m][n][r] + bval);
                *(short4v*)(outB + ((size_t)(b * H_ + h) * 64 + d) * NKP + kk0) = sv;
            }
        }
    }
}

// --- fused attention: logits + mask + softmax + att write + PV -------------
template <typename MT>
static __device__ __forceinline__ void mask_scale_pass(f32x4* s, const MT* __restrict__ m,
                                                       size_t mrow0, int wid, int l15, int lg) {
#pragma unroll
    for (int t = 0; t < 17; t++) {
        int kk = (wid * 17 + t) * 16 + l15;
#pragma unroll
        for (int r = 0; r < 4; r++) {
            float v = s[t][r] * 0.125f;
            if (kk >= NKM) {
                v = -INFINITY;
            } else if (kk < NK) {
                if (m[(mrow0 + lg * 4 + r) * NK + kk]) v = -INFINITY;
            }
            s[t][r] = v;
        }
    }
}

__global__ __launch_bounds__(256) void attn_kernel(
    const short* __restrict__ Qh, const short* __restrict__ Kh,
    const short* __restrict__ Vt,
    const unsigned char* __restrict__ mb, const int* __restrict__ mi,
    const int* __restrict__ flag,
    float* __restrict__ att, short* __restrict__ Ow) {
    __shared__ float redM[4][16];
    __shared__ float redS[4][16];
    __shared__ short Plds[4][16][40];   // per-wave P tile (pair of 16-col tiles)
    __shared__ float Ored[4][16][64];

    // XCD swizzle: 8192 blocks, 1024 consecutive per XCD => 16 bh per XCD
    int swz = (blockIdx.x & 7) * 1024 + (blockIdx.x >> 3);
    int bh = swz >> 6;
    int qt = swz & 63;
    int lane = threadIdx.x & 63;
    int wid = threadIdx.x >> 6;
    int l15 = lane & 15, lg = lane >> 4;
    int q0 = qt * 16;

    const short* Qb = Qh + ((size_t)bh * NQ + q0) * 64;
    const short* Kb = Kh + (size_t)bh * NKP * 64;
    const short* Vb = Vt + (size_t)bh * 64 * NKP;

    bf16x8 aq0 = *(const bf16x8*)(Qb + (size_t)l15 * 64 + lg * 8);
    bf16x8 aq1 = *(const bf16x8*)(Qb + (size_t)l15 * 64 + 32 + lg * 8);

    // S = Q K^T for this wave's 17 kk-tiles
    f32x4 s[17];
#pragma unroll
    for (int t = 0; t < 17; t++) {
        int kt = wid * 17 + t;
        const short* Kr = Kb + (size_t)(kt * 16 + l15) * 64;
        bf16x8 k0 = *(const bf16x8*)(Kr + lg * 8);
        bf16x8 k1 = *(const bf16x8*)(Kr + 32 + lg * 8);
        f32x4 a = f32x4{0.f, 0.f, 0.f, 0.f};
        a = __builtin_amdgcn_mfma_f32_16x16x32_bf16(aq0, k0, a, 0, 0, 0);
        a = __builtin_amdgcn_mfma_f32_16x16x32_bf16(aq1, k1, a, 0, 0, 0);
        s[t] = a;
    }

    // scale + mask (uniform branch on mask dtype; no speculative OOB loads)
    size_t mrow0 = (size_t)bh * NQ + q0;
    if (*flag) mask_scale_pass(s, mi, mrow0, wid, l15, lg);
    else       mask_scale_pass(s, mb, mrow0, wid, l15, lg);

    // block row-max
    float mx[4];
#pragma unroll
    for (int r = 0; r < 4; r++) {
        float m = s[0][r];
#pragma unroll
        for (int t = 1; t < 17; t++) m = fmaxf(m, s[t][r]);
#pragma unroll
        for (int o = 8; o; o >>= 1) m = fmaxf(m, __shfl_xor(m, o));
        mx[r] = m;
    }
    if (l15 == 0) {
#pragma unroll
        for (int r = 0; r < 4; r++) redM[wid][lg * 4 + r] = mx[r];
    }
    __syncthreads();
#pragma unroll
    for (int r = 0; r < 4; r++) {
        int rowid = lg * 4 + r;
        mx[r] = fmaxf(fmaxf(redM[0][rowid], redM[1][rowid]),
                      fmaxf(redM[2][rowid], redM[3][rowid]));
    }

    // exp + block row-sum
    float sm[4] = {0.f, 0.f, 0.f, 0.f};
#pragma unroll
    for (int t = 0; t < 17; t++) {
#pragma unroll
        for (int r = 0; r < 4; r++) {
            float e = __expf(s[t][r] - mx[r]);
            s[t][r] = e;
            sm[r] += e;
        }
    }
#pragma unroll
    for (int r = 0; r < 4; r++) {
#pragma unroll
        for (int o = 8; o; o >>= 1) sm[r] += __shfl_xor(sm[r], o);
    }
    if (l15 == 0) {
#pragma unroll
        for (int r = 0; r < 4; r++) redS[wid][lg * 4 + r] = sm[r];
    }
    __syncthreads();
    float inv[4];
#pragma unroll
    for (int r = 0; r < 4; r++) {
        int rowid = lg * 4 + r;
        inv[r] = 1.f / (redS[0][rowid] + redS[1][rowid] + redS[2][rowid] + redS[3][rowid]);
    }

    // PV over pairs of tiles (32 kk per MFMA) + att stores
    f32x4 po[4];
#pragma unroll
    for (int dt = 0; dt < 4; dt++) po[dt] = f32x4{0.f, 0.f, 0.f, 0.f};

#pragma unroll
    for (int pp = 0; pp < 9; pp++) {
#pragma unroll
        for (int tl = 0; tl < 2; tl++) {
            int t = pp * 2 + tl;
            if (t < 17) {
                int kk = (wid * 17 + t) * 16 + l15;
#pragma unroll
                for (int r = 0; r < 4; r++) {
                    float p = s[t][r] * inv[r];
                    if (kk < NKM) {
                        int q = q0 + lg * 4 + r;
                        att[((size_t)bh * NQ + q) * NKM + kk] = p;
                    }
                    Plds[wid][lg * 4 + r][tl * 16 + l15] = f2bf(p);
                }
            } else {
#pragma unroll
                for (int r = 0; r < 4; r++)
                    Plds[wid][lg * 4 + r][tl * 16 + l15] = 0;   // zero absent half
            }
        }
        bf16x8 ap = *(const bf16x8*)(&Plds[wid][l15][lg * 8]);
        int kk0 = wid * 272 + pp * 32;
#pragma unroll
        for (int dt = 0; dt < 4; dt++) {
            bf16x8 bv = *(const bf16x8*)(Vb + (size_t)(dt * 16 + l15) * NKP + kk0 + lg * 8);
            po[dt] = __builtin_amdgcn_mfma_f32_16x16x32_bf16(ap, bv, po[dt], 0, 0, 0);
        }
    }

    // cross-wave O reduction -> Ow bf16
#pragma unroll
    for (int dt = 0; dt < 4; dt++)
#pragma unroll
        for (int r = 0; r < 4; r++)
            Ored[wid][lg * 4 + r][dt * 16 + l15] = po[dt][r];
    __syncthreads();
    int tq = threadIdx.x >> 4;           // 0..15
    int d0 = (threadIdx.x & 15) * 4;     // 0..60
    float4 o = {0.f, 0.f, 0.f, 0.f};
#pragma unroll
    for (int w = 0; w < 4; w++) {
        float4 v = *(const float4*)(&Ored[w][tq][d0]);
        o.x += v.x; o.y += v.y; o.z += v.z; o.w += v.w;
    }
    int b = bh >> 4, h = bh & 15;
    short4v sv;
    sv[0] = f2bf(o.x); sv[1] = f2bf(o.y); sv[2] = f2bf(o.z); sv[3] = f2bf(o.w);
    *(short4v*)(Ow + ((size_t)(b * NQ) + q0 + tq) * DM + h * 64 + d0) = sv;
}

extern "C" void kernel_launch(void* const* d_in, const int* in_sizes, int n_in,
                              void* d_out, int out_size, void* d_ws, size_t ws_size,
                              hipStream_t stream) {
    const float* queries = (const float*)d_in[0];
    const float* keys    = (const float*)d_in[1];
    const float* values  = (const float*)d_in[2];
    const void*  mask    = d_in[3];
    const float* Wq = (const float*)d_in[4];
    const float* bq = (const float*)d_in[5];
    const float* Wk = (const float*)d_in[6];
    const float* bk = (const float*)d_in[7];
    const float* Wv = (const float*)d_in[8];
    const float* bv = (const float*)d_in[9];
    const float* Wo = (const float*)d_in[10];
    const float* bo = (const float*)d_in[11];
    const float* m_k = (const float*)d_in[12];
    const float* m_v = (const float*)d_in[13];

    // workspace layout (shorts) — ~78.2 MB total
    short* WqT = (short*)d_ws;
    short* WkT = WqT + (size_t)DM * DM;
    short* WvT = WkT + (size_t)DM * DM;
    short* WoT = WvT + (size_t)DM * DM;
    short* Qh  = WoT + (size_t)DM * DM;                 // [128][1024][64]
    short* Kh  = Qh + (size_t)B_ * H_ * NQ * DK;        // [128][1104][64]
    short* Vt  = Kh + (size_t)B_ * H_ * NKP * DK;       // [128][64][1104]
    short* Ow  = Vt + (size_t)B_ * H_ * DK * NKP;       // [8192][1024]
    int* flag  = (int*)(Ow + (size_t)B_ * NQ * DM);

    float* outO = (float*)d_out;                         // 8*1024*1024
    float* att  = outO + (size_t)B_ * NQ * DM;           // 8*16*1024*1064

    detect_mask_kernel<<<1, 256, 0, stream>>>((const unsigned int*)mask, 4096, flag);

    dim3 tg(32, 32);
    transpose_w_kernel<<<tg, 256, 0, stream>>>(Wq, WqT);
    transpose_w_kernel<<<tg, 256, 0, stream>>>(Wk, WkT);
    transpose_w_kernel<<<tg, 256, 0, stream>>>(Wv, WvT);
    transpose_w_kernel<<<tg, 256, 0, stream>>>(Wo, WoT);

    gemm_tile_kernel<0><<<512, 256, 0, stream>>>(queries, nullptr, WqT, bq, nullptr, Qh);
    gemm_tile_kernel<1><<<512, 256, 0, stream>>>(keys,    nullptr, WkT, bk, nullptr, Kh);
    gemm_tile_kernel<2><<<512, 256, 0, stream>>>(values,  nullptr, WvT, bv, nullptr, Vt);

    fill_mem_kernel<<<2560, 256, 0, stream>>>(m_k, m_v, Kh, Vt);

    attn_kernel<<<8192, 256, 0, stream>>>(Qh, Kh, Vt,
                                          (const unsigned char*)mask, (const int*)mask,
                                          flag, att, Ow);

    gemm_tile_kernel<3><<<512, 256, 0, stream>>>(nullptr, Ow, WoT, bo, outO, Qh /*unused*/);
}